// Round 15
// baseline (227.128 us; speedup 1.0000x reference)
//
#include <hip/hip_runtime.h>
#include <stdint.h>

typedef float  f32x4  __attribute__((ext_vector_type(4)));
typedef short  short8 __attribute__((ext_vector_type(8)));

#define DEV __device__ __forceinline__

#define L2E  1.4426950408889634f
#define L2E2 2.8853900817779268f

// raw v_exp_f32 (2^x); inputs bounded so no libm guard code needed
DEV float ex2(float x){ float r; asm("v_exp_f32 %0, %1" : "=v"(r) : "v"(x)); return r; }
// packed f32x2 -> bf16x2
DEV unsigned cvtpk_bf16(float lo, float hi){
  unsigned r; asm("v_cvt_pk_bf16_f32 %0, %1, %2" : "=v"(r) : "v"(lo), "v"(hi)); return r;
}

DEV unsigned short f2bf(float x){
  union { float f; unsigned u; } v; v.f = x;
  unsigned r = v.u + 0x7fffu + ((v.u >> 16) & 1u);   // RNE
  return (unsigned short)(r >> 16);
}
// tanh(x) for raw x
DEV float tanhx_(float x){ return 1.f - 2.f*__builtin_amdgcn_rcpf(1.f + ex2(x*L2E2)); }
// activations on PRE-SCALED inputs: z_sig = -log2e*z, z_tanh = 2log2e*z
DEV float sig_ps(float z){ return __builtin_amdgcn_rcpf(1.f + ex2(z)); }
DEV float tanh_ps(float z){ return 1.f - 2.f*__builtin_amdgcn_rcpf(1.f + ex2(z)); }

// async global->LDS, 16 B per lane (wave-uniform base + lane*16 dest)
DEV void gload_lds16(const void* g, void* l){
  __builtin_amdgcn_global_load_lds(
      (const __attribute__((address_space(1))) unsigned int*)g,
      (__attribute__((address_space(3))) unsigned int*)l, 16, 0, 0);
}

// ---------------------------------------------------------------------------
// Merged prep (r14-verified): transposes for Wh/W2/Wc + copy out[3].
//   blocks 0..3583   : WcT  (swz, 8 x 448)
//   blocks 3584..3647: WhT  (gate-scaled, 16 x 4)
//   blocks 3648..3711: W2T  (8 x 8)
//   blocks 3712..4095: copy_out3 (384)
// ---------------------------------------------------------------------------
DEV void tr_body(const float* __restrict__ src, unsigned short* __restrict__ dst,
                 int R, int C, int bx, int by, bool swz, bool gscale)
{
  __shared__ float tile[32][33];
  const int tx = threadIdx.x & 31, ty = threadIdx.x >> 5;
  const int c0 = bx * 32, r0 = by * 32;
  #pragma unroll
  for (int m = 0; m < 4; ++m){
    int r = ty + m*8;
    tile[r][tx] = src[(size_t)(r0 + r) * C + (c0 + tx)];
  }
  __syncthreads();
  #pragma unroll
  for (int m = 0; m < 4; ++m){
    int cc = c0 + ty + m*8;
    int k  = r0 + tx;
    int k2 = swz ? (k ^ ((cc & 7) << 3)) : k;
    float v = tile[tx][ty + m*8];
    if (gscale) v *= ((cc >> 7) == 2) ? L2E2 : -L2E;
    dst[(size_t)cc * R + k2] = f2bf(v);
  }
}

__global__ void __launch_bounds__(256) prep_k(
    const float* __restrict__ Wh, const float* __restrict__ W2,
    const float* __restrict__ Wc, const float* __restrict__ inputs,
    unsigned short* __restrict__ WhT, unsigned short* __restrict__ W2T,
    unsigned short* __restrict__ WcT, float* __restrict__ out3)
{
  const int bid = blockIdx.x;
  if (bid < 3584){
    tr_body(Wc, WcT, 14336, 256, bid & 7, bid >> 3, true, false);
  } else if (bid < 3648){
    int b = bid - 3584;
    tr_body(Wh, WhT, 128, 512, b & 15, b >> 4, false, true);
  } else if (bid < 3712){
    int b = bid - 3648;
    tr_body(W2, W2T, 256, 256, b & 7, b >> 3, false, false);
  } else {
    int i = (bid - 3712) * 256 + threadIdx.x;      // 98304 float4s
    int n = i / 24, q = i - n*24;
    f32x4 v = *(const f32x4*)(inputs + (size_t)n*128 + 32 + q*4);
    *(f32x4*)(out3 + (size_t)n*96 + q*4) = v;
  }
}

// ---------------------------------------------------------------------------
// LSTM warm-up + autoregressive rollout (r7-verified source, 16 samples/block).
// ---------------------------------------------------------------------------
__global__ void __launch_bounds__(512, 2) lstm_k(
    const float* __restrict__ inputs, const float* __restrict__ Wi,
    const unsigned short* __restrict__ WhT, const float* __restrict__ bl,
    const float* __restrict__ Wp, const float* __restrict__ bp,
    unsigned short* __restrict__ concat, float* __restrict__ out0)
{
  __shared__ __align__(16) unsigned char hbuf[2*16*16*16];   // ping-pong [kgrp][row][16B]
  __shared__ __align__(16) unsigned char hwu[16*16*256];     // warm-up h [t][s][256B]
  __shared__ float predb[48][16][2];                         // AR preds
  __shared__ float xwu[16][33];                              // warm-up inputs (padded)
  const int tid = threadIdx.x, lane = tid & 63, w = tid >> 6;
  const int n0 = blockIdx.x * 16;
  const int col = lane & 15;
  const int u = w*16 + col;
  const int rbase = (lane >> 4) * 4;

  { int s = tid >> 5, e = tid & 31;
    xwu[s][e] = inputs[(size_t)(n0 + s)*128 + e]; }

  short8 bfrag[4][4];
  #pragma unroll
  for (int g = 0; g < 4; ++g){
    const unsigned short* p = WhT + (size_t)(g*128 + u) * 128;
    #pragma unroll
    for (int kt = 0; kt < 4; ++kt)
      bfrag[g][kt] = *(const short8*)(p + kt*32 + (lane >> 4)*8);
  }
  short8 wpf[4];
  #pragma unroll
  for (int kt = 0; kt < 4; ++kt){
    short8 v;
    #pragma unroll
    for (int j = 0; j < 8; ++j){
      int k = kt*32 + (lane >> 4)*8 + j;
      v[j] = (short)f2bf(Wp[k*2 + (col & 1)]);
    }
    wpf[kt] = v;
  }
  float wi0[4], wi1[4];
  f32x4 bbv[4];
  #pragma unroll
  for (int g = 0; g < 4; ++g){
    int c = g*128 + u;
    float sc = (g == 2) ? L2E2 : -L2E;
    wi0[g] = Wi[c] * sc; wi1[g] = Wi[512 + c] * sc;
    float b = bl[c] * sc;
    bbv[g] = (f32x4){b, b, b, b};
  }
  const float bpv = bp[col & 1];
  const f32x4 bpvv = (f32x4){bpv, bpv, bpv, bpv};
  float cst[4] = {0.f, 0.f, 0.f, 0.f};
  __syncthreads();

  #pragma unroll 1
  for (int t = 0; t < 64; ++t){
    const unsigned char* rd = hbuf + ((t + 1) & 1) * 4096;
    unsigned char*       wr = hbuf + (t & 1) * 4096;
    short8 afr[4];
    if (t > 0){
      #pragma unroll
      for (int kt = 0; kt < 4; ++kt)
        afr[kt] = *(const short8*)(rd + (kt*4 + (lane >> 4))*256 + col*16);
    }
    float x0[4], x1[4];
    if (t < 16){
      #pragma unroll
      for (int i = 0; i < 4; ++i){
        x0[i] = xwu[rbase + i][t*2]; x1[i] = xwu[rbase + i][t*2 + 1];
      }
    } else {
      f32x4 pacc = __builtin_amdgcn_mfma_f32_16x16x32_bf16(afr[0], wpf[0], bpvv, 0, 0, 0);
      pacc = __builtin_amdgcn_mfma_f32_16x16x32_bf16(afr[1], wpf[1], pacc, 0, 0, 0);
      pacc = __builtin_amdgcn_mfma_f32_16x16x32_bf16(afr[2], wpf[2], pacc, 0, 0, 0);
      pacc = __builtin_amdgcn_mfma_f32_16x16x32_bf16(afr[3], wpf[3], pacc, 0, 0, 0);
      float val[4];
      #pragma unroll
      for (int i = 0; i < 4; ++i) val[i] = tanhx_(pacc[i]);
      #pragma unroll
      for (int i = 0; i < 4; ++i){
        float ov_ = __shfl_xor(val[i], 1);
        x0[i] = (col & 1) ? ov_ : val[i];
        x1[i] = (col & 1) ? val[i] : ov_;
      }
      if (w == 0 && col < 2 && t >= 17){
        #pragma unroll
        for (int i = 0; i < 4; ++i) predb[t - 17][rbase + i][col] = val[i];
      }
    }
    f32x4 acc[4];
    if (t > 0){
      #pragma unroll
      for (int g = 0; g < 4; ++g)
        acc[g] = __builtin_amdgcn_mfma_f32_16x16x32_bf16(afr[0], bfrag[g][0], bbv[g], 0, 0, 0);
      #pragma unroll
      for (int kt = 1; kt < 4; ++kt){
        #pragma unroll
        for (int g = 0; g < 4; ++g)
          acc[g] = __builtin_amdgcn_mfma_f32_16x16x32_bf16(afr[kt], bfrag[g][kt], acc[g], 0, 0, 0);
      }
    } else {
      #pragma unroll
      for (int g = 0; g < 4; ++g) acc[g] = bbv[g];
    }
    float hf[4];
    #pragma unroll
    for (int i = 0; i < 4; ++i){
      float z0 = acc[0][i] + x0[i]*wi0[0] + x1[i]*wi1[0];
      float z1 = acc[1][i] + x0[i]*wi0[1] + x1[i]*wi1[1];
      float z2 = acc[2][i] + x0[i]*wi0[2] + x1[i]*wi1[2];
      float z3 = acc[3][i] + x0[i]*wi0[3] + x1[i]*wi1[3];
      float iv = sig_ps(z0), fv = sig_ps(z1), gv = tanh_ps(z2), ov = sig_ps(z3);
      float c = fv*cst[i] + iv*gv;
      cst[i] = c;
      hf[i] = ov * tanhx_(c);
    }
    unsigned p01 = cvtpk_bf16(hf[0], hf[1]);
    unsigned p23 = cvtpk_bf16(hf[2], hf[3]);
    unsigned short hb[4] = {
      (unsigned short)(p01 & 0xffffu), (unsigned short)(p01 >> 16),
      (unsigned short)(p23 & 0xffffu), (unsigned short)(p23 >> 16) };
    #pragma unroll
    for (int i = 0; i < 4; ++i){
      int r = rbase + i;
      *(unsigned short*)(wr + (u >> 3)*256 + r*16 + (u & 7)*2) = hb[i];
      if (t < 16)
        *(unsigned short*)(hwu + t*4096 + r*256 + u*2) = hb[i];
    }
    __syncthreads();
  }
  // epilogue: pred(63)
  {
    const unsigned char* rd = hbuf + 4096;
    short8 afr[4];
    #pragma unroll
    for (int kt = 0; kt < 4; ++kt)
      afr[kt] = *(const short8*)(rd + (kt*4 + (lane >> 4))*256 + col*16);
    f32x4 pacc = __builtin_amdgcn_mfma_f32_16x16x32_bf16(afr[0], wpf[0], bpvv, 0, 0, 0);
    pacc = __builtin_amdgcn_mfma_f32_16x16x32_bf16(afr[1], wpf[1], pacc, 0, 0, 0);
    pacc = __builtin_amdgcn_mfma_f32_16x16x32_bf16(afr[2], wpf[2], pacc, 0, 0, 0);
    pacc = __builtin_amdgcn_mfma_f32_16x16x32_bf16(afr[3], wpf[3], pacc, 0, 0, 0);
    if (w == 0 && col < 2){
      #pragma unroll
      for (int i = 0; i < 4; ++i) predb[47][rbase + i][col] = tanhx_(pacc[i]);
    }
  }
  __syncthreads();
  // flush warm-up h -> concat (pre-swizzled for ev staging)
  for (int idx = tid; idx < 4096; idx += 512){
    int t = idx >> 8, s = (idx >> 4) & 15, j = idx & 15;
    short8 v = *(const short8*)(hwu + t*4096 + s*256 + j*16);
    *(short8*)((unsigned char*)concat + (size_t)(n0 + s)*28672
        + ((unsigned)(t*256 + j*16) ^ ((s & 7) << 4))) = v;
  }
  // flush preds -> out0
  for (int idx = tid; idx < 1536; idx += 512){
    int s = idx / 96, r = idx - s*96;
    out0[(size_t)(n0 + s)*96 + r] = predb[r >> 1][s][r & 1];
  }
}

// ---------------------------------------------------------------------------
// t1 = tanh(preds@W1+b1); t2 = tanh(t1@W2+b2) -> concat[:, 2048 + t*256 + c]
// (r7-verified source, unmodified)
// ---------------------------------------------------------------------------
__global__ void __launch_bounds__(256) t1t2_k(
    const float* __restrict__ preds, const float* __restrict__ W1,
    const float* __restrict__ b1, const unsigned short* __restrict__ W2T,
    const float* __restrict__ b2, unsigned short* __restrict__ concat)
{
  __shared__ __align__(16) unsigned char t1buf[16*512];   // bf16 [16][256] swizzled
  const int tid = threadIdx.x, lane = tid & 63, w = tid >> 6;

  short8 bfrag[4][8];
  {
    const int krow = (lane >> 4) * 8;
    #pragma unroll
    for (int nt = 0; nt < 4; ++nt){
      const unsigned short* p = W2T + (size_t)(w*64 + nt*16 + (lane & 15)) * 256;
      #pragma unroll
      for (int kt = 0; kt < 8; ++kt){
        bfrag[nt][kt] = *(const short8*)(p + kt*32 + krow);
      }
    }
  }
  float b2c[4];
  #pragma unroll
  for (int nt = 0; nt < 4; ++nt) b2c[nt] = b2[w*64 + nt*16 + (lane & 15)];
  float w1a[16], w1b[16], b1c[16];
  {
    const int k0 = (tid & 15) * 16;
    #pragma unroll
    for (int j = 0; j < 16; ++j){
      w1a[j] = W1[k0 + j]; w1b[j] = W1[256 + k0 + j]; b1c[j] = b1[k0 + j];
    }
  }
  const int lr = tid >> 4, k0 = (tid & 15) * 16;

  #pragma unroll 1
  for (int rt = 0; rt < 8; ++rt){
    const int r0 = blockIdx.x * 128 + rt * 16;
    {
      const float p0 = preds[(size_t)(r0 + lr)*2 + 0];
      const float p1 = preds[(size_t)(r0 + lr)*2 + 1];
      const int sw = (lr & 7) << 4;
      #pragma unroll
      for (int h = 0; h < 2; ++h){
        short8 t1v;
        #pragma unroll
        for (int j = 0; j < 8; ++j){
          int jj = h*8 + j;
          t1v[j] = (short)f2bf(tanhx_(p0*w1a[jj] + p1*w1b[jj] + b1c[jj]));
        }
        *(short8*)(t1buf + ((lr*512 + (k0 + h*8)*2) ^ sw)) = t1v;
      }
    }
    __syncthreads();
    f32x4 acc[4];
    #pragma unroll
    for (int nt = 0; nt < 4; ++nt) acc[nt] = (f32x4){0.f,0.f,0.f,0.f};
    {
      const int row = lane & 15;
      const int sw = (row & 7) << 4;
      #pragma unroll
      for (int kt = 0; kt < 8; ++kt){
        short8 a = *(const short8*)(t1buf + ((row*512 + (kt*32 + (lane>>4)*8)*2) ^ sw));
        #pragma unroll
        for (int nt = 0; nt < 4; ++nt){
          acc[nt] = __builtin_amdgcn_mfma_f32_16x16x32_bf16(a, bfrag[nt][kt], acc[nt], 0, 0, 0);
        }
      }
    }
    #pragma unroll
    for (int nt = 0; nt < 4; ++nt){
      const int col = w*64 + nt*16 + (lane & 15);
      #pragma unroll
      for (int i = 0; i < 4; ++i){
        int m = r0 + (lane >> 4)*4 + i;
        int n = m / 48, tt = m - n*48;
        unsigned short val = f2bf(tanhx_(acc[nt][i] + b2c[nt]));
        *(unsigned short*)((unsigned char*)concat + (size_t)n*28672
            + ((unsigned)((2048 + tt*256 + col)*2) ^ ((n & 7) << 4))) = val;
      }
    }
    __syncthreads();
  }
}

// ---------------------------------------------------------------------------
// ev GEMM v5: r14-verified fragments/XCD decode; staging switched to async
// global_load_lds width-16 (m97 2-barrier structure). concat/WcT are
// pre-swizzled so staging is LINEAR: LDS slot o = tid*16 + j*8192 maps to
// row = o>>7, byte = o&127 (same layout the swizzled ds_reads expect).
// ---------------------------------------------------------------------------
__global__ void __launch_bounds__(512, 2) ev_k(
    const unsigned short* __restrict__ concat, const unsigned short* __restrict__ WcT,
    float* __restrict__ partials)
{
  __shared__ __align__(16) unsigned char Abuf[128*128];   // bf16 [128 rows][64 k]
  __shared__ __align__(16) unsigned char Bbuf[256*128];   // bf16 [256 cols][64 k]
  const int tid = threadIdx.x, lane = tid & 63, w = tid >> 6;
  const int wm = w >> 2, wn = w & 3;
  const int yk = blockIdx.x & 7, xr = blockIdx.x >> 3;
  const int n0 = xr * 128;
  const int kbase = yk * 1792;

  f32x4 acc[4][4];
  #pragma unroll
  for (int mt = 0; mt < 4; ++mt)
    #pragma unroll
    for (int nt = 0; nt < 4; ++nt) acc[mt][nt] = (f32x4){0.f,0.f,0.f,0.f};

  // per-thread linear staging slots (constant row/byte decode, hoisted)
  const int ao0 = tid*16,          ar0_ = ao0 >> 7, ac0_ = ao0 & 127;
  const int ao1 = tid*16 + 8192,   ar1_ = ao1 >> 7, ac1_ = ao1 & 127;
  const unsigned char* cbase = (const unsigned char*)concat;
  const unsigned char* wbase = (const unsigned char*)WcT;

  #pragma unroll 1
  for (int ch = 0; ch < 28; ++ch){
    const int kk2 = (kbase + ch*64) * 2;
    // stage A: 16 KB via 2 async copies/thread
    gload_lds16(cbase + (size_t)(n0 + ar0_)*28672 + kk2 + ac0_, Abuf + ao0);
    gload_lds16(cbase + (size_t)(n0 + ar1_)*28672 + kk2 + ac1_, Abuf + ao1);
    // stage B: 32 KB via 4 async copies/thread
    #pragma unroll
    for (int j = 0; j < 4; ++j){
      int o = tid*16 + j*8192;
      int bc = o >> 7, bb = o & 127;
      gload_lds16(wbase + (size_t)bc*28672 + kk2 + bb, Bbuf + o);
    }
    __syncthreads();   // drains vmcnt (compiler) + barrier: tiles ready
    #pragma unroll
    for (int kt = 0; kt < 2; ++kt){
      const int kby = kt*64 + (lane >> 4)*16;
      short8 afr[4], bfr[4];
      #pragma unroll
      for (int mt = 0; mt < 4; ++mt){
        int row = wm*64 + mt*16 + (lane & 15);
        afr[mt] = *(const short8*)(Abuf + ((row*128 + kby) ^ ((row & 7) << 4)));
      }
      #pragma unroll
      for (int nt = 0; nt < 4; ++nt){
        int col = wn*64 + nt*16 + (lane & 15);
        bfr[nt] = *(const short8*)(Bbuf + ((col*128 + kby) ^ ((col & 7) << 4)));
      }
      #pragma unroll
      for (int mt = 0; mt < 4; ++mt)
        #pragma unroll
        for (int nt = 0; nt < 4; ++nt)
          acc[mt][nt] = __builtin_amdgcn_mfma_f32_16x16x32_bf16(afr[mt], bfr[nt], acc[mt][nt], 0, 0, 0);
    }
    __syncthreads();   // all reads done before next stage overwrites
  }
  float* dst = partials + (size_t)yk * (4096*256);
  #pragma unroll
  for (int mt = 0; mt < 4; ++mt){
    #pragma unroll
    for (int nt = 0; nt < 4; ++nt){
      #pragma unroll
      for (int i = 0; i < 4; ++i){
        int n = n0 + wm*64 + mt*16 + (lane >> 4)*4 + i;
        int col = wn*64 + nt*16 + (lane & 15);
        dst[(size_t)n*256 + col] = acc[mt][nt][i];
      }
    }
  }
}

// ---------------------------------------------------------------------------
// Reduce 8 partial slots, ev = tanh(.+bc), prob softmax + cost (r7-verified).
// ---------------------------------------------------------------------------
__global__ void __launch_bounds__(256) heads_k(
    const float* __restrict__ partials, const float* __restrict__ bc,
    const float* __restrict__ Wprob, const float* __restrict__ bprob,
    const float* __restrict__ Wasso, const float* __restrict__ basso,
    float* __restrict__ out1, float* __restrict__ out2)
{
  __shared__ float evs[16][257];
  const int tid = threadIdx.x;
  const int nl = tid >> 4, part = tid & 15;
  const int n = blockIdx.x * 16 + nl;
  #pragma unroll
  for (int q = 0; q < 4; ++q){
    const int c = part*16 + q*4;
    f32x4 s = {0.f,0.f,0.f,0.f};
    #pragma unroll
    for (int p = 0; p < 8; ++p){
      s += *(const f32x4*)(partials + (size_t)p*1048576 + (size_t)n*256 + c);
    }
    #pragma unroll
    for (int j = 0; j < 4; ++j) evs[nl][c + j] = tanhx_(s[j] + bc[c + j]);
  }
  __syncthreads();
  float s0 = 0.f, s1 = 0.f, s2 = 0.f;
  #pragma unroll
  for (int j = 0; j < 16; ++j){
    int c = part*16 + j;
    float e = evs[nl][c];
    s0 += e * Wprob[c*2];
    s1 += e * Wprob[c*2 + 1];
    s2 += e * Wasso[c];
  }
  s0 += __shfl_xor(s0, 1); s1 += __shfl_xor(s1, 1); s2 += __shfl_xor(s2, 1);
  s0 += __shfl_xor(s0, 2); s1 += __shfl_xor(s1, 2); s2 += __shfl_xor(s2, 2);
  s0 += __shfl_xor(s0, 4); s1 += __shfl_xor(s1, 4); s2 += __shfl_xor(s2, 4);
  s0 += __shfl_xor(s0, 8); s1 += __shfl_xor(s1, 8); s2 += __shfl_xor(s2, 8);
  if (part == 0){
    float a0 = s0 + bprob[0], a1 = s1 + bprob[1];
    float m = fmaxf(a0, a1);
    float e0 = ex2((a0 - m)*L2E), e1 = ex2((a1 - m)*L2E);
    float inv = __builtin_amdgcn_rcpf(e0 + e1);
    out2[(size_t)n*96 + 0] = e0 * inv;
    out2[(size_t)n*96 + 1] = e1 * inv;
    out1[(size_t)n*96 + 0] = s2 + basso[0];
  }
}

// ---------------------------------------------------------------------------
extern "C" void kernel_launch(void* const* d_in, const int* in_sizes, int n_in,
                              void* d_out, int out_size, void* d_ws, size_t ws_size,
                              hipStream_t stream)
{
  (void)in_sizes; (void)n_in; (void)ws_size;
  const float* inputs = (const float*)d_in[0];
  const float* Wi     = (const float*)d_in[1];
  const float* Wh     = (const float*)d_in[2];
  const float* bl     = (const float*)d_in[3];
  const float* Wp     = (const float*)d_in[4];
  const float* bp     = (const float*)d_in[5];
  const float* W1     = (const float*)d_in[6];
  const float* b1     = (const float*)d_in[7];
  const float* W2     = (const float*)d_in[8];
  const float* b2     = (const float*)d_in[9];
  const float* Wc     = (const float*)d_in[10];
  const float* bc     = (const float*)d_in[11];
  const float* Wprob  = (const float*)d_in[12];
  const float* bprob  = (const float*)d_in[13];
  const float* Wasso  = (const float*)d_in[14];
  const float* basso  = (const float*)d_in[15];
  float* out = (float*)d_out;

  // workspace layout (r7-identical footprint: 158,597,120 B)
  char* ws = (char*)d_ws;
  unsigned short* concat = (unsigned short*)ws;                 // [4096][14336] bf16 swizzled
  unsigned short* WhT    = (unsigned short*)(ws + 117440512);   // [512][128] bf16 (gate-scaled)
  unsigned short* W2T    = (unsigned short*)(ws + 117571584);   // [256][256] bf16 raw
  unsigned short* WcT    = (unsigned short*)(ws + 117702656);   // [256][14336] bf16 swizzled
  float*          parts  = (float*)(ws + 125042688);            // [8][4096][256] f32

  hipMemsetAsync(d_out, 0, (size_t)out_size * sizeof(float), stream);
  dim3 blk(256);
  prep_k<<<4096, blk, 0, stream>>>(Wh, W2, Wc, inputs, WhT, W2T, WcT, out + 3*393216);
  lstm_k<<<256, dim3(512), 0, stream>>>(inputs, Wi, WhT, bl, Wp, bp, concat, out);
  t1t2_k<<<1536, blk, 0, stream>>>(out, W1, b1, W2T, b2, concat);
  ev_k<<<256, dim3(512), 0, stream>>>(concat, WcT, parts);
  heads_k<<<256, blk, 0, stream>>>(parts, bc, Wprob, bprob, Wasso, basso,
                                   out + 393216, out + 2*393216);
}

// Round 16
// 225.200 us; speedup vs baseline: 1.0086x; 1.0086x over previous
//
#include <hip/hip_runtime.h>
#include <stdint.h>

typedef float  f32x4  __attribute__((ext_vector_type(4)));
typedef short  short8 __attribute__((ext_vector_type(8)));

#define DEV __device__ __forceinline__

#define L2E  1.4426950408889634f
#define L2E2 2.8853900817779268f

// raw v_exp_f32 (2^x); inputs bounded so no libm guard code needed
DEV float ex2(float x){ float r; asm("v_exp_f32 %0, %1" : "=v"(r) : "v"(x)); return r; }
// packed f32x2 -> bf16x2
DEV unsigned cvtpk_bf16(float lo, float hi){
  unsigned r; asm("v_cvt_pk_bf16_f32 %0, %1, %2" : "=v"(r) : "v"(lo), "v"(hi)); return r;
}

DEV unsigned short f2bf(float x){
  union { float f; unsigned u; } v; v.f = x;
  unsigned r = v.u + 0x7fffu + ((v.u >> 16) & 1u);   // RNE
  return (unsigned short)(r >> 16);
}
// tanh(x) for raw x
DEV float tanhx_(float x){ return 1.f - 2.f*__builtin_amdgcn_rcpf(1.f + ex2(x*L2E2)); }
// activations on PRE-SCALED inputs: z_sig = -log2e*z, z_tanh = 2log2e*z
DEV float sig_ps(float z){ return __builtin_amdgcn_rcpf(1.f + ex2(z)); }
DEV float tanh_ps(float z){ return 1.f - 2.f*__builtin_amdgcn_rcpf(1.f + ex2(z)); }

// ---------------------------------------------------------------------------
// Merged prep (r14-verified): transposes for Wh/W2/Wc + copy out[3].
//   blocks 0..3583   : WcT  (swz, 8 x 448)
//   blocks 3584..3647: WhT  (gate-scaled, 16 x 4)
//   blocks 3648..3711: W2T  (8 x 8)
//   blocks 3712..4095: copy_out3 (384)
// ---------------------------------------------------------------------------
DEV void tr_body(const float* __restrict__ src, unsigned short* __restrict__ dst,
                 int R, int C, int bx, int by, bool swz, bool gscale)
{
  __shared__ float tile[32][33];
  const int tx = threadIdx.x & 31, ty = threadIdx.x >> 5;
  const int c0 = bx * 32, r0 = by * 32;
  #pragma unroll
  for (int m = 0; m < 4; ++m){
    int r = ty + m*8;
    tile[r][tx] = src[(size_t)(r0 + r) * C + (c0 + tx)];
  }
  __syncthreads();
  #pragma unroll
  for (int m = 0; m < 4; ++m){
    int cc = c0 + ty + m*8;
    int k  = r0 + tx;
    int k2 = swz ? (k ^ ((cc & 7) << 3)) : k;
    float v = tile[tx][ty + m*8];
    if (gscale) v *= ((cc >> 7) == 2) ? L2E2 : -L2E;
    dst[(size_t)cc * R + k2] = f2bf(v);
  }
}

__global__ void __launch_bounds__(256) prep_k(
    const float* __restrict__ Wh, const float* __restrict__ W2,
    const float* __restrict__ Wc, const float* __restrict__ inputs,
    unsigned short* __restrict__ WhT, unsigned short* __restrict__ W2T,
    unsigned short* __restrict__ WcT, float* __restrict__ out3)
{
  const int bid = blockIdx.x;
  if (bid < 3584){
    tr_body(Wc, WcT, 14336, 256, bid & 7, bid >> 3, true, false);
  } else if (bid < 3648){
    int b = bid - 3584;
    tr_body(Wh, WhT, 128, 512, b & 15, b >> 4, false, true);
  } else if (bid < 3712){
    int b = bid - 3648;
    tr_body(W2, W2T, 256, 256, b & 7, b >> 3, false, false);
  } else {
    int i = (bid - 3712) * 256 + threadIdx.x;      // 98304 float4s
    int n = i / 24, q = i - n*24;
    f32x4 v = *(const f32x4*)(inputs + (size_t)n*128 + 32 + q*4);
    *(f32x4*)(out3 + (size_t)n*96 + q*4) = v;
  }
}

// ---------------------------------------------------------------------------
// LSTM warm-up + autoregressive rollout (r7-verified source, 16 samples/block).
// ---------------------------------------------------------------------------
__global__ void __launch_bounds__(512, 2) lstm_k(
    const float* __restrict__ inputs, const float* __restrict__ Wi,
    const unsigned short* __restrict__ WhT, const float* __restrict__ bl,
    const float* __restrict__ Wp, const float* __restrict__ bp,
    unsigned short* __restrict__ concat, float* __restrict__ out0)
{
  __shared__ __align__(16) unsigned char hbuf[2*16*16*16];   // ping-pong [kgrp][row][16B]
  __shared__ __align__(16) unsigned char hwu[16*16*256];     // warm-up h [t][s][256B]
  __shared__ float predb[48][16][2];                         // AR preds
  __shared__ float xwu[16][33];                              // warm-up inputs (padded)
  const int tid = threadIdx.x, lane = tid & 63, w = tid >> 6;
  const int n0 = blockIdx.x * 16;
  const int col = lane & 15;
  const int u = w*16 + col;
  const int rbase = (lane >> 4) * 4;

  { int s = tid >> 5, e = tid & 31;
    xwu[s][e] = inputs[(size_t)(n0 + s)*128 + e]; }

  short8 bfrag[4][4];
  #pragma unroll
  for (int g = 0; g < 4; ++g){
    const unsigned short* p = WhT + (size_t)(g*128 + u) * 128;
    #pragma unroll
    for (int kt = 0; kt < 4; ++kt)
      bfrag[g][kt] = *(const short8*)(p + kt*32 + (lane >> 4)*8);
  }
  short8 wpf[4];
  #pragma unroll
  for (int kt = 0; kt < 4; ++kt){
    short8 v;
    #pragma unroll
    for (int j = 0; j < 8; ++j){
      int k = kt*32 + (lane >> 4)*8 + j;
      v[j] = (short)f2bf(Wp[k*2 + (col & 1)]);
    }
    wpf[kt] = v;
  }
  float wi0[4], wi1[4];
  f32x4 bbv[4];
  #pragma unroll
  for (int g = 0; g < 4; ++g){
    int c = g*128 + u;
    float sc = (g == 2) ? L2E2 : -L2E;
    wi0[g] = Wi[c] * sc; wi1[g] = Wi[512 + c] * sc;
    float b = bl[c] * sc;
    bbv[g] = (f32x4){b, b, b, b};
  }
  const float bpv = bp[col & 1];
  const f32x4 bpvv = (f32x4){bpv, bpv, bpv, bpv};
  float cst[4] = {0.f, 0.f, 0.f, 0.f};
  __syncthreads();

  #pragma unroll 1
  for (int t = 0; t < 64; ++t){
    const unsigned char* rd = hbuf + ((t + 1) & 1) * 4096;
    unsigned char*       wr = hbuf + (t & 1) * 4096;
    short8 afr[4];
    if (t > 0){
      #pragma unroll
      for (int kt = 0; kt < 4; ++kt)
        afr[kt] = *(const short8*)(rd + (kt*4 + (lane >> 4))*256 + col*16);
    }
    float x0[4], x1[4];
    if (t < 16){
      #pragma unroll
      for (int i = 0; i < 4; ++i){
        x0[i] = xwu[rbase + i][t*2]; x1[i] = xwu[rbase + i][t*2 + 1];
      }
    } else {
      f32x4 pacc = __builtin_amdgcn_mfma_f32_16x16x32_bf16(afr[0], wpf[0], bpvv, 0, 0, 0);
      pacc = __builtin_amdgcn_mfma_f32_16x16x32_bf16(afr[1], wpf[1], pacc, 0, 0, 0);
      pacc = __builtin_amdgcn_mfma_f32_16x16x32_bf16(afr[2], wpf[2], pacc, 0, 0, 0);
      pacc = __builtin_amdgcn_mfma_f32_16x16x32_bf16(afr[3], wpf[3], pacc, 0, 0, 0);
      float val[4];
      #pragma unroll
      for (int i = 0; i < 4; ++i) val[i] = tanhx_(pacc[i]);
      #pragma unroll
      for (int i = 0; i < 4; ++i){
        float ov_ = __shfl_xor(val[i], 1);
        x0[i] = (col & 1) ? ov_ : val[i];
        x1[i] = (col & 1) ? val[i] : ov_;
      }
      if (w == 0 && col < 2 && t >= 17){
        #pragma unroll
        for (int i = 0; i < 4; ++i) predb[t - 17][rbase + i][col] = val[i];
      }
    }
    f32x4 acc[4];
    if (t > 0){
      #pragma unroll
      for (int g = 0; g < 4; ++g)
        acc[g] = __builtin_amdgcn_mfma_f32_16x16x32_bf16(afr[0], bfrag[g][0], bbv[g], 0, 0, 0);
      #pragma unroll
      for (int kt = 1; kt < 4; ++kt){
        #pragma unroll
        for (int g = 0; g < 4; ++g)
          acc[g] = __builtin_amdgcn_mfma_f32_16x16x32_bf16(afr[kt], bfrag[g][kt], acc[g], 0, 0, 0);
      }
    } else {
      #pragma unroll
      for (int g = 0; g < 4; ++g) acc[g] = bbv[g];
    }
    float hf[4];
    #pragma unroll
    for (int i = 0; i < 4; ++i){
      float z0 = acc[0][i] + x0[i]*wi0[0] + x1[i]*wi1[0];
      float z1 = acc[1][i] + x0[i]*wi0[1] + x1[i]*wi1[1];
      float z2 = acc[2][i] + x0[i]*wi0[2] + x1[i]*wi1[2];
      float z3 = acc[3][i] + x0[i]*wi0[3] + x1[i]*wi1[3];
      float iv = sig_ps(z0), fv = sig_ps(z1), gv = tanh_ps(z2), ov = sig_ps(z3);
      float c = fv*cst[i] + iv*gv;
      cst[i] = c;
      hf[i] = ov * tanhx_(c);
    }
    unsigned p01 = cvtpk_bf16(hf[0], hf[1]);
    unsigned p23 = cvtpk_bf16(hf[2], hf[3]);
    unsigned short hb[4] = {
      (unsigned short)(p01 & 0xffffu), (unsigned short)(p01 >> 16),
      (unsigned short)(p23 & 0xffffu), (unsigned short)(p23 >> 16) };
    #pragma unroll
    for (int i = 0; i < 4; ++i){
      int r = rbase + i;
      *(unsigned short*)(wr + (u >> 3)*256 + r*16 + (u & 7)*2) = hb[i];
      if (t < 16)
        *(unsigned short*)(hwu + t*4096 + r*256 + u*2) = hb[i];
    }
    __syncthreads();
  }
  // epilogue: pred(63)
  {
    const unsigned char* rd = hbuf + 4096;
    short8 afr[4];
    #pragma unroll
    for (int kt = 0; kt < 4; ++kt)
      afr[kt] = *(const short8*)(rd + (kt*4 + (lane >> 4))*256 + col*16);
    f32x4 pacc = __builtin_amdgcn_mfma_f32_16x16x32_bf16(afr[0], wpf[0], bpvv, 0, 0, 0);
    pacc = __builtin_amdgcn_mfma_f32_16x16x32_bf16(afr[1], wpf[1], pacc, 0, 0, 0);
    pacc = __builtin_amdgcn_mfma_f32_16x16x32_bf16(afr[2], wpf[2], pacc, 0, 0, 0);
    pacc = __builtin_amdgcn_mfma_f32_16x16x32_bf16(afr[3], wpf[3], pacc, 0, 0, 0);
    if (w == 0 && col < 2){
      #pragma unroll
      for (int i = 0; i < 4; ++i) predb[47][rbase + i][col] = tanhx_(pacc[i]);
    }
  }
  __syncthreads();
  // flush warm-up h -> concat (pre-swizzled for ev staging)
  for (int idx = tid; idx < 4096; idx += 512){
    int t = idx >> 8, s = (idx >> 4) & 15, j = idx & 15;
    short8 v = *(const short8*)(hwu + t*4096 + s*256 + j*16);
    *(short8*)((unsigned char*)concat + (size_t)(n0 + s)*28672
        + ((unsigned)(t*256 + j*16) ^ ((s & 7) << 4))) = v;
  }
  // flush preds -> out0
  for (int idx = tid; idx < 1536; idx += 512){
    int s = idx / 96, r = idx - s*96;
    out0[(size_t)(n0 + s)*96 + r] = predb[r >> 1][s][r & 1];
  }
}

// ---------------------------------------------------------------------------
// t1 = tanh(preds@W1+b1); t2 = tanh(t1@W2+b2) -> concat[:, 2048 + t*256 + c]
// (r7-verified source, unmodified)
// ---------------------------------------------------------------------------
__global__ void __launch_bounds__(256) t1t2_k(
    const float* __restrict__ preds, const float* __restrict__ W1,
    const float* __restrict__ b1, const unsigned short* __restrict__ W2T,
    const float* __restrict__ b2, unsigned short* __restrict__ concat)
{
  __shared__ __align__(16) unsigned char t1buf[16*512];   // bf16 [16][256] swizzled
  const int tid = threadIdx.x, lane = tid & 63, w = tid >> 6;

  short8 bfrag[4][8];
  {
    const int krow = (lane >> 4) * 8;
    #pragma unroll
    for (int nt = 0; nt < 4; ++nt){
      const unsigned short* p = W2T + (size_t)(w*64 + nt*16 + (lane & 15)) * 256;
      #pragma unroll
      for (int kt = 0; kt < 8; ++kt){
        bfrag[nt][kt] = *(const short8*)(p + kt*32 + krow);
      }
    }
  }
  float b2c[4];
  #pragma unroll
  for (int nt = 0; nt < 4; ++nt) b2c[nt] = b2[w*64 + nt*16 + (lane & 15)];
  float w1a[16], w1b[16], b1c[16];
  {
    const int k0 = (tid & 15) * 16;
    #pragma unroll
    for (int j = 0; j < 16; ++j){
      w1a[j] = W1[k0 + j]; w1b[j] = W1[256 + k0 + j]; b1c[j] = b1[k0 + j];
    }
  }
  const int lr = tid >> 4, k0 = (tid & 15) * 16;

  #pragma unroll 1
  for (int rt = 0; rt < 8; ++rt){
    const int r0 = blockIdx.x * 128 + rt * 16;
    {
      const float p0 = preds[(size_t)(r0 + lr)*2 + 0];
      const float p1 = preds[(size_t)(r0 + lr)*2 + 1];
      const int sw = (lr & 7) << 4;
      #pragma unroll
      for (int h = 0; h < 2; ++h){
        short8 t1v;
        #pragma unroll
        for (int j = 0; j < 8; ++j){
          int jj = h*8 + j;
          t1v[j] = (short)f2bf(tanhx_(p0*w1a[jj] + p1*w1b[jj] + b1c[jj]));
        }
        *(short8*)(t1buf + ((lr*512 + (k0 + h*8)*2) ^ sw)) = t1v;
      }
    }
    __syncthreads();
    f32x4 acc[4];
    #pragma unroll
    for (int nt = 0; nt < 4; ++nt) acc[nt] = (f32x4){0.f,0.f,0.f,0.f};
    {
      const int row = lane & 15;
      const int sw = (row & 7) << 4;
      #pragma unroll
      for (int kt = 0; kt < 8; ++kt){
        short8 a = *(const short8*)(t1buf + ((row*512 + (kt*32 + (lane>>4)*8)*2) ^ sw));
        #pragma unroll
        for (int nt = 0; nt < 4; ++nt){
          acc[nt] = __builtin_amdgcn_mfma_f32_16x16x32_bf16(a, bfrag[nt][kt], acc[nt], 0, 0, 0);
        }
      }
    }
    #pragma unroll
    for (int nt = 0; nt < 4; ++nt){
      const int col = w*64 + nt*16 + (lane & 15);
      #pragma unroll
      for (int i = 0; i < 4; ++i){
        int m = r0 + (lane >> 4)*4 + i;
        int n = m / 48, tt = m - n*48;
        unsigned short val = f2bf(tanhx_(acc[nt][i] + b2c[nt]));
        *(unsigned short*)((unsigned char*)concat + (size_t)n*28672
            + ((unsigned)((2048 + tt*256 + col)*2) ^ ((n & 7) << 4))) = val;
      }
    }
    __syncthreads();
  }
}

// ---------------------------------------------------------------------------
// ev GEMM (r14-verified): reg-staged prefetch + XCD-clustered 1D grid 256.
// y = wgid&7 (k-slice), x = wgid>>3 (row-tile) -> blocks sharing a B-slice
// land on the same XCD -> B stays L2-resident.
// ---------------------------------------------------------------------------
__global__ void __launch_bounds__(512, 2) ev_k(
    const unsigned short* __restrict__ concat, const unsigned short* __restrict__ WcT,
    float* __restrict__ partials)
{
  __shared__ __align__(16) unsigned char Abuf[128*128];   // bf16 [128 rows][64 k]
  __shared__ __align__(16) unsigned char Bbuf[256*128];   // bf16 [256 cols][64 k]
  const int tid = threadIdx.x, lane = tid & 63, w = tid >> 6;
  const int wm = w >> 2, wn = w & 3;
  const int yk = blockIdx.x & 7, xr = blockIdx.x >> 3;
  const int n0 = xr * 128;
  const int kbase = yk * 1792;

  f32x4 acc[4][4];
  #pragma unroll
  for (int mt = 0; mt < 4; ++mt)
    #pragma unroll
    for (int nt = 0; nt < 4; ++nt) acc[mt][nt] = (f32x4){0.f,0.f,0.f,0.f};

  const int aoff = tid * 32;
  const int arow = aoff >> 7;
  const unsigned char* asrc = (const unsigned char*)concat + (size_t)(n0 + arow)*28672 + (aoff & 127);
  const int bcol = tid >> 1, bhalf = (tid & 1) * 64;
  const unsigned char* bsrc = (const unsigned char*)WcT + (size_t)bcol*28672 + bhalf;

  // prologue: load chunk 0
  short8 ar0 = *(const short8*)(asrc + kbase*2);
  short8 ar1 = *(const short8*)(asrc + kbase*2 + 16);
  short8 br[4];
  #pragma unroll
  for (int kb = 0; kb < 4; ++kb) br[kb] = *(const short8*)(bsrc + kbase*2 + kb*16);

  #pragma unroll 1
  for (int ch = 0; ch < 28; ++ch){
    __syncthreads();
    *(short8*)(Abuf + aoff)      = ar0;
    *(short8*)(Abuf + aoff + 16) = ar1;
    #pragma unroll
    for (int kb = 0; kb < 4; ++kb) *(short8*)(Bbuf + bcol*128 + bhalf + kb*16) = br[kb];
    __syncthreads();
    if (ch < 27){  // issue next-chunk loads; latency hides under the MFMAs
      const int kk2 = (kbase + (ch + 1)*64) * 2;
      ar0 = *(const short8*)(asrc + kk2);
      ar1 = *(const short8*)(asrc + kk2 + 16);
      #pragma unroll
      for (int kb = 0; kb < 4; ++kb) br[kb] = *(const short8*)(bsrc + kk2 + kb*16);
    }
    #pragma unroll
    for (int kt = 0; kt < 2; ++kt){
      const int kby = kt*64 + (lane >> 4)*16;
      short8 afr[4], bfr[4];
      #pragma unroll
      for (int mt = 0; mt < 4; ++mt){
        int row = wm*64 + mt*16 + (lane & 15);
        afr[mt] = *(const short8*)(Abuf + ((row*128 + kby) ^ ((row & 7) << 4)));
      }
      #pragma unroll
      for (int nt = 0; nt < 4; ++nt){
        int col = wn*64 + nt*16 + (lane & 15);
        bfr[nt] = *(const short8*)(Bbuf + ((col*128 + kby) ^ ((col & 7) << 4)));
      }
      #pragma unroll
      for (int mt = 0; mt < 4; ++mt)
        #pragma unroll
        for (int nt = 0; nt < 4; ++nt)
          acc[mt][nt] = __builtin_amdgcn_mfma_f32_16x16x32_bf16(afr[mt], bfr[nt], acc[mt][nt], 0, 0, 0);
    }
  }
  float* dst = partials + (size_t)yk * (4096*256);
  #pragma unroll
  for (int mt = 0; mt < 4; ++mt){
    #pragma unroll
    for (int nt = 0; nt < 4; ++nt){
      #pragma unroll
      for (int i = 0; i < 4; ++i){
        int n = n0 + wm*64 + mt*16 + (lane >> 4)*4 + i;
        int col = wn*64 + nt*16 + (lane & 15);
        dst[(size_t)n*256 + col] = acc[mt][nt][i];
      }
    }
  }
}

// ---------------------------------------------------------------------------
// Reduce 8 partial slots, ev = tanh(.+bc), prob softmax + cost (r7-verified).
// ---------------------------------------------------------------------------
__global__ void __launch_bounds__(256) heads_k(
    const float* __restrict__ partials, const float* __restrict__ bc,
    const float* __restrict__ Wprob, const float* __restrict__ bprob,
    const float* __restrict__ Wasso, const float* __restrict__ basso,
    float* __restrict__ out1, float* __restrict__ out2)
{
  __shared__ float evs[16][257];
  const int tid = threadIdx.x;
  const int nl = tid >> 4, part = tid & 15;
  const int n = blockIdx.x * 16 + nl;
  #pragma unroll
  for (int q = 0; q < 4; ++q){
    const int c = part*16 + q*4;
    f32x4 s = {0.f,0.f,0.f,0.f};
    #pragma unroll
    for (int p = 0; p < 8; ++p){
      s += *(const f32x4*)(partials + (size_t)p*1048576 + (size_t)n*256 + c);
    }
    #pragma unroll
    for (int j = 0; j < 4; ++j) evs[nl][c + j] = tanhx_(s[j] + bc[c + j]);
  }
  __syncthreads();
  float s0 = 0.f, s1 = 0.f, s2 = 0.f;
  #pragma unroll
  for (int j = 0; j < 16; ++j){
    int c = part*16 + j;
    float e = evs[nl][c];
    s0 += e * Wprob[c*2];
    s1 += e * Wprob[c*2 + 1];
    s2 += e * Wasso[c];
  }
  s0 += __shfl_xor(s0, 1); s1 += __shfl_xor(s1, 1); s2 += __shfl_xor(s2, 1);
  s0 += __shfl_xor(s0, 2); s1 += __shfl_xor(s1, 2); s2 += __shfl_xor(s2, 2);
  s0 += __shfl_xor(s0, 4); s1 += __shfl_xor(s1, 4); s2 += __shfl_xor(s2, 4);
  s0 += __shfl_xor(s0, 8); s1 += __shfl_xor(s1, 8); s2 += __shfl_xor(s2, 8);
  if (part == 0){
    float a0 = s0 + bprob[0], a1 = s1 + bprob[1];
    float m = fmaxf(a0, a1);
    float e0 = ex2((a0 - m)*L2E), e1 = ex2((a1 - m)*L2E);
    float inv = __builtin_amdgcn_rcpf(e0 + e1);
    out2[(size_t)n*96 + 0] = e0 * inv;
    out2[(size_t)n*96 + 1] = e1 * inv;
    out1[(size_t)n*96 + 0] = s2 + basso[0];
  }
}

// ---------------------------------------------------------------------------
extern "C" void kernel_launch(void* const* d_in, const int* in_sizes, int n_in,
                              void* d_out, int out_size, void* d_ws, size_t ws_size,
                              hipStream_t stream)
{
  (void)in_sizes; (void)n_in; (void)ws_size;
  const float* inputs = (const float*)d_in[0];
  const float* Wi     = (const float*)d_in[1];
  const float* Wh     = (const float*)d_in[2];
  const float* bl     = (const float*)d_in[3];
  const float* Wp     = (const float*)d_in[4];
  const float* bp     = (const float*)d_in[5];
  const float* W1     = (const float*)d_in[6];
  const float* b1     = (const float*)d_in[7];
  const float* W2     = (const float*)d_in[8];
  const float* b2     = (const float*)d_in[9];
  const float* Wc     = (const float*)d_in[10];
  const float* bc     = (const float*)d_in[11];
  const float* Wprob  = (const float*)d_in[12];
  const float* bprob  = (const float*)d_in[13];
  const float* Wasso  = (const float*)d_in[14];
  const float* basso  = (const float*)d_in[15];
  float* out = (float*)d_out;

  // workspace layout (r7-identical footprint: 158,597,120 B)
  char* ws = (char*)d_ws;
  unsigned short* concat = (unsigned short*)ws;                 // [4096][14336] bf16 swizzled
  unsigned short* WhT    = (unsigned short*)(ws + 117440512);   // [512][128] bf16 (gate-scaled)
  unsigned short* W2T    = (unsigned short*)(ws + 117571584);   // [256][256] bf16 raw
  unsigned short* WcT    = (unsigned short*)(ws + 117702656);   // [256][14336] bf16 swizzled
  float*          parts  = (float*)(ws + 125042688);            // [8][4096][256] f32

  hipMemsetAsync(d_out, 0, (size_t)out_size * sizeof(float), stream);
  dim3 blk(256);
  prep_k<<<4096, blk, 0, stream>>>(Wh, W2, Wc, inputs, WhT, W2T, WcT, out + 3*393216);
  lstm_k<<<256, dim3(512), 0, stream>>>(inputs, Wi, WhT, bl, Wp, bp, concat, out);
  t1t2_k<<<1536, blk, 0, stream>>>(out, W1, b1, W2T, b2, concat);
  ev_k<<<256, dim3(512), 0, stream>>>(concat, WcT, parts);
  heads_k<<<256, blk, 0, stream>>>(parts, bc, Wprob, bprob, Wasso, basso,
                                   out + 393216, out + 2*393216);
}

// Round 17
// 219.943 us; speedup vs baseline: 1.0327x; 1.0239x over previous
//
#include <hip/hip_runtime.h>
#include <stdint.h>

typedef float  f32x4  __attribute__((ext_vector_type(4)));
typedef short  short8 __attribute__((ext_vector_type(8)));

#define DEV __device__ __forceinline__

#define L2E  1.4426950408889634f
#define L2E2 2.8853900817779268f

// raw v_exp_f32 (2^x); inputs bounded so no libm guard code needed
DEV float ex2(float x){ float r; asm("v_exp_f32 %0, %1" : "=v"(r) : "v"(x)); return r; }
// packed f32x2 -> bf16x2
DEV unsigned cvtpk_bf16(float lo, float hi){
  unsigned r; asm("v_cvt_pk_bf16_f32 %0, %1, %2" : "=v"(r) : "v"(lo), "v"(hi)); return r;
}

DEV unsigned short f2bf(float x){
  union { float f; unsigned u; } v; v.f = x;
  unsigned r = v.u + 0x7fffu + ((v.u >> 16) & 1u);   // RNE
  return (unsigned short)(r >> 16);
}
// tanh(x) for raw x
DEV float tanhx_(float x){ return 1.f - 2.f*__builtin_amdgcn_rcpf(1.f + ex2(x*L2E2)); }
// activations on PRE-SCALED inputs: z_sig = -log2e*z, z_tanh = 2log2e*z
DEV float sig_ps(float z){ return __builtin_amdgcn_rcpf(1.f + ex2(z)); }
DEV float tanh_ps(float z){ return 1.f - 2.f*__builtin_amdgcn_rcpf(1.f + ex2(z)); }

// ---------------------------------------------------------------------------
// Merged prep (r14-verified): transposes for Wh/W2/Wc + copy out[3].
//   blocks 0..3583   : WcT  (swz, 8 x 448)
//   blocks 3584..3647: WhT  (gate-scaled, 16 x 4)
//   blocks 3648..3711: W2T  (8 x 8)
//   blocks 3712..4095: copy_out3 (384)
// ---------------------------------------------------------------------------
DEV void tr_body(const float* __restrict__ src, unsigned short* __restrict__ dst,
                 int R, int C, int bx, int by, bool swz, bool gscale)
{
  __shared__ float tile[32][33];
  const int tx = threadIdx.x & 31, ty = threadIdx.x >> 5;
  const int c0 = bx * 32, r0 = by * 32;
  #pragma unroll
  for (int m = 0; m < 4; ++m){
    int r = ty + m*8;
    tile[r][tx] = src[(size_t)(r0 + r) * C + (c0 + tx)];
  }
  __syncthreads();
  #pragma unroll
  for (int m = 0; m < 4; ++m){
    int cc = c0 + ty + m*8;
    int k  = r0 + tx;
    int k2 = swz ? (k ^ ((cc & 7) << 3)) : k;
    float v = tile[tx][ty + m*8];
    if (gscale) v *= ((cc >> 7) == 2) ? L2E2 : -L2E;
    dst[(size_t)cc * R + k2] = f2bf(v);
  }
}

__global__ void __launch_bounds__(256) prep_k(
    const float* __restrict__ Wh, const float* __restrict__ W2,
    const float* __restrict__ Wc, const float* __restrict__ inputs,
    unsigned short* __restrict__ WhT, unsigned short* __restrict__ W2T,
    unsigned short* __restrict__ WcT, float* __restrict__ out3)
{
  const int bid = blockIdx.x;
  if (bid < 3584){
    tr_body(Wc, WcT, 14336, 256, bid & 7, bid >> 3, true, false);
  } else if (bid < 3648){
    int b = bid - 3584;
    tr_body(Wh, WhT, 128, 512, b & 15, b >> 4, false, true);
  } else if (bid < 3712){
    int b = bid - 3648;
    tr_body(W2, W2T, 256, 256, b & 7, b >> 3, false, false);
  } else {
    int i = (bid - 3712) * 256 + threadIdx.x;      // 98304 float4s
    int n = i / 24, q = i - n*24;
    f32x4 v = *(const f32x4*)(inputs + (size_t)n*128 + 32 + q*4);
    *(f32x4*)(out3 + (size_t)n*96 + q*4) = v;
  }
}

// ---------------------------------------------------------------------------
// LSTM warm-up + autoregressive rollout (r7-verified source, 16 samples/block).
// ---------------------------------------------------------------------------
__global__ void __launch_bounds__(512, 2) lstm_k(
    const float* __restrict__ inputs, const float* __restrict__ Wi,
    const unsigned short* __restrict__ WhT, const float* __restrict__ bl,
    const float* __restrict__ Wp, const float* __restrict__ bp,
    unsigned short* __restrict__ concat, float* __restrict__ out0)
{
  __shared__ __align__(16) unsigned char hbuf[2*16*16*16];   // ping-pong [kgrp][row][16B]
  __shared__ __align__(16) unsigned char hwu[16*16*256];     // warm-up h [t][s][256B]
  __shared__ float predb[48][16][2];                         // AR preds
  __shared__ float xwu[16][33];                              // warm-up inputs (padded)
  const int tid = threadIdx.x, lane = tid & 63, w = tid >> 6;
  const int n0 = blockIdx.x * 16;
  const int col = lane & 15;
  const int u = w*16 + col;
  const int rbase = (lane >> 4) * 4;

  { int s = tid >> 5, e = tid & 31;
    xwu[s][e] = inputs[(size_t)(n0 + s)*128 + e]; }

  short8 bfrag[4][4];
  #pragma unroll
  for (int g = 0; g < 4; ++g){
    const unsigned short* p = WhT + (size_t)(g*128 + u) * 128;
    #pragma unroll
    for (int kt = 0; kt < 4; ++kt)
      bfrag[g][kt] = *(const short8*)(p + kt*32 + (lane >> 4)*8);
  }
  short8 wpf[4];
  #pragma unroll
  for (int kt = 0; kt < 4; ++kt){
    short8 v;
    #pragma unroll
    for (int j = 0; j < 8; ++j){
      int k = kt*32 + (lane >> 4)*8 + j;
      v[j] = (short)f2bf(Wp[k*2 + (col & 1)]);
    }
    wpf[kt] = v;
  }
  float wi0[4], wi1[4];
  f32x4 bbv[4];
  #pragma unroll
  for (int g = 0; g < 4; ++g){
    int c = g*128 + u;
    float sc = (g == 2) ? L2E2 : -L2E;
    wi0[g] = Wi[c] * sc; wi1[g] = Wi[512 + c] * sc;
    float b = bl[c] * sc;
    bbv[g] = (f32x4){b, b, b, b};
  }
  const float bpv = bp[col & 1];
  const f32x4 bpvv = (f32x4){bpv, bpv, bpv, bpv};
  float cst[4] = {0.f, 0.f, 0.f, 0.f};
  __syncthreads();

  #pragma unroll 1
  for (int t = 0; t < 64; ++t){
    const unsigned char* rd = hbuf + ((t + 1) & 1) * 4096;
    unsigned char*       wr = hbuf + (t & 1) * 4096;
    short8 afr[4];
    if (t > 0){
      #pragma unroll
      for (int kt = 0; kt < 4; ++kt)
        afr[kt] = *(const short8*)(rd + (kt*4 + (lane >> 4))*256 + col*16);
    }
    float x0[4], x1[4];
    if (t < 16){
      #pragma unroll
      for (int i = 0; i < 4; ++i){
        x0[i] = xwu[rbase + i][t*2]; x1[i] = xwu[rbase + i][t*2 + 1];
      }
    } else {
      f32x4 pacc = __builtin_amdgcn_mfma_f32_16x16x32_bf16(afr[0], wpf[0], bpvv, 0, 0, 0);
      pacc = __builtin_amdgcn_mfma_f32_16x16x32_bf16(afr[1], wpf[1], pacc, 0, 0, 0);
      pacc = __builtin_amdgcn_mfma_f32_16x16x32_bf16(afr[2], wpf[2], pacc, 0, 0, 0);
      pacc = __builtin_amdgcn_mfma_f32_16x16x32_bf16(afr[3], wpf[3], pacc, 0, 0, 0);
      float val[4];
      #pragma unroll
      for (int i = 0; i < 4; ++i) val[i] = tanhx_(pacc[i]);
      #pragma unroll
      for (int i = 0; i < 4; ++i){
        float ov_ = __shfl_xor(val[i], 1);
        x0[i] = (col & 1) ? ov_ : val[i];
        x1[i] = (col & 1) ? val[i] : ov_;
      }
      if (w == 0 && col < 2 && t >= 17){
        #pragma unroll
        for (int i = 0; i < 4; ++i) predb[t - 17][rbase + i][col] = val[i];
      }
    }
    f32x4 acc[4];
    if (t > 0){
      #pragma unroll
      for (int g = 0; g < 4; ++g)
        acc[g] = __builtin_amdgcn_mfma_f32_16x16x32_bf16(afr[0], bfrag[g][0], bbv[g], 0, 0, 0);
      #pragma unroll
      for (int kt = 1; kt < 4; ++kt){
        #pragma unroll
        for (int g = 0; g < 4; ++g)
          acc[g] = __builtin_amdgcn_mfma_f32_16x16x32_bf16(afr[kt], bfrag[g][kt], acc[g], 0, 0, 0);
      }
    } else {
      #pragma unroll
      for (int g = 0; g < 4; ++g) acc[g] = bbv[g];
    }
    float hf[4];
    #pragma unroll
    for (int i = 0; i < 4; ++i){
      float z0 = acc[0][i] + x0[i]*wi0[0] + x1[i]*wi1[0];
      float z1 = acc[1][i] + x0[i]*wi0[1] + x1[i]*wi1[1];
      float z2 = acc[2][i] + x0[i]*wi0[2] + x1[i]*wi1[2];
      float z3 = acc[3][i] + x0[i]*wi0[3] + x1[i]*wi1[3];
      float iv = sig_ps(z0), fv = sig_ps(z1), gv = tanh_ps(z2), ov = sig_ps(z3);
      float c = fv*cst[i] + iv*gv;
      cst[i] = c;
      hf[i] = ov * tanhx_(c);
    }
    unsigned p01 = cvtpk_bf16(hf[0], hf[1]);
    unsigned p23 = cvtpk_bf16(hf[2], hf[3]);
    unsigned short hb[4] = {
      (unsigned short)(p01 & 0xffffu), (unsigned short)(p01 >> 16),
      (unsigned short)(p23 & 0xffffu), (unsigned short)(p23 >> 16) };
    #pragma unroll
    for (int i = 0; i < 4; ++i){
      int r = rbase + i;
      *(unsigned short*)(wr + (u >> 3)*256 + r*16 + (u & 7)*2) = hb[i];
      if (t < 16)
        *(unsigned short*)(hwu + t*4096 + r*256 + u*2) = hb[i];
    }
    __syncthreads();
  }
  // epilogue: pred(63)
  {
    const unsigned char* rd = hbuf + 4096;
    short8 afr[4];
    #pragma unroll
    for (int kt = 0; kt < 4; ++kt)
      afr[kt] = *(const short8*)(rd + (kt*4 + (lane >> 4))*256 + col*16);
    f32x4 pacc = __builtin_amdgcn_mfma_f32_16x16x32_bf16(afr[0], wpf[0], bpvv, 0, 0, 0);
    pacc = __builtin_amdgcn_mfma_f32_16x16x32_bf16(afr[1], wpf[1], pacc, 0, 0, 0);
    pacc = __builtin_amdgcn_mfma_f32_16x16x32_bf16(afr[2], wpf[2], pacc, 0, 0, 0);
    pacc = __builtin_amdgcn_mfma_f32_16x16x32_bf16(afr[3], wpf[3], pacc, 0, 0, 0);
    if (w == 0 && col < 2){
      #pragma unroll
      for (int i = 0; i < 4; ++i) predb[47][rbase + i][col] = tanhx_(pacc[i]);
    }
  }
  __syncthreads();
  // flush warm-up h -> concat (pre-swizzled for ev staging)
  for (int idx = tid; idx < 4096; idx += 512){
    int t = idx >> 8, s = (idx >> 4) & 15, j = idx & 15;
    short8 v = *(const short8*)(hwu + t*4096 + s*256 + j*16);
    *(short8*)((unsigned char*)concat + (size_t)(n0 + s)*28672
        + ((unsigned)(t*256 + j*16) ^ ((s & 7) << 4))) = v;
  }
  // flush preds -> out0
  for (int idx = tid; idx < 1536; idx += 512){
    int s = idx / 96, r = idx - s*96;
    out0[(size_t)(n0 + s)*96 + r] = predb[r >> 1][s][r & 1];
  }
}

// ---------------------------------------------------------------------------
// t1 = tanh(preds@W1+b1); t2 = tanh(t1@W2+b2) -> concat[:, 2048 + t*256 + c]
// (r7-verified source, unmodified)
// ---------------------------------------------------------------------------
__global__ void __launch_bounds__(256) t1t2_k(
    const float* __restrict__ preds, const float* __restrict__ W1,
    const float* __restrict__ b1, const unsigned short* __restrict__ W2T,
    const float* __restrict__ b2, unsigned short* __restrict__ concat)
{
  __shared__ __align__(16) unsigned char t1buf[16*512];   // bf16 [16][256] swizzled
  const int tid = threadIdx.x, lane = tid & 63, w = tid >> 6;

  short8 bfrag[4][8];
  {
    const int krow = (lane >> 4) * 8;
    #pragma unroll
    for (int nt = 0; nt < 4; ++nt){
      const unsigned short* p = W2T + (size_t)(w*64 + nt*16 + (lane & 15)) * 256;
      #pragma unroll
      for (int kt = 0; kt < 8; ++kt){
        bfrag[nt][kt] = *(const short8*)(p + kt*32 + krow);
      }
    }
  }
  float b2c[4];
  #pragma unroll
  for (int nt = 0; nt < 4; ++nt) b2c[nt] = b2[w*64 + nt*16 + (lane & 15)];
  float w1a[16], w1b[16], b1c[16];
  {
    const int k0 = (tid & 15) * 16;
    #pragma unroll
    for (int j = 0; j < 16; ++j){
      w1a[j] = W1[k0 + j]; w1b[j] = W1[256 + k0 + j]; b1c[j] = b1[k0 + j];
    }
  }
  const int lr = tid >> 4, k0 = (tid & 15) * 16;

  #pragma unroll 1
  for (int rt = 0; rt < 8; ++rt){
    const int r0 = blockIdx.x * 128 + rt * 16;
    {
      const float p0 = preds[(size_t)(r0 + lr)*2 + 0];
      const float p1 = preds[(size_t)(r0 + lr)*2 + 1];
      const int sw = (lr & 7) << 4;
      #pragma unroll
      for (int h = 0; h < 2; ++h){
        short8 t1v;
        #pragma unroll
        for (int j = 0; j < 8; ++j){
          int jj = h*8 + j;
          t1v[j] = (short)f2bf(tanhx_(p0*w1a[jj] + p1*w1b[jj] + b1c[jj]));
        }
        *(short8*)(t1buf + ((lr*512 + (k0 + h*8)*2) ^ sw)) = t1v;
      }
    }
    __syncthreads();
    f32x4 acc[4];
    #pragma unroll
    for (int nt = 0; nt < 4; ++nt) acc[nt] = (f32x4){0.f,0.f,0.f,0.f};
    {
      const int row = lane & 15;
      const int sw = (row & 7) << 4;
      #pragma unroll
      for (int kt = 0; kt < 8; ++kt){
        short8 a = *(const short8*)(t1buf + ((row*512 + (kt*32 + (lane>>4)*8)*2) ^ sw));
        #pragma unroll
        for (int nt = 0; nt < 4; ++nt){
          acc[nt] = __builtin_amdgcn_mfma_f32_16x16x32_bf16(a, bfrag[nt][kt], acc[nt], 0, 0, 0);
        }
      }
    }
    #pragma unroll
    for (int nt = 0; nt < 4; ++nt){
      const int col = w*64 + nt*16 + (lane & 15);
      #pragma unroll
      for (int i = 0; i < 4; ++i){
        int m = r0 + (lane >> 4)*4 + i;
        int n = m / 48, tt = m - n*48;
        unsigned short val = f2bf(tanhx_(acc[nt][i] + b2c[nt]));
        *(unsigned short*)((unsigned char*)concat + (size_t)n*28672
            + ((unsigned)((2048 + tt*256 + col)*2) ^ ((n & 7) << 4))) = val;
      }
    }
    __syncthreads();
  }
}

// ---------------------------------------------------------------------------
// ev GEMM (r14-verified): reg-staged prefetch + XCD-clustered 1D grid 256.
// y = wgid&7 (k-slice), x = wgid>>3 (row-tile) -> blocks sharing a B-slice
// land on the same XCD -> B stays L2-resident.
// ---------------------------------------------------------------------------
__global__ void __launch_bounds__(512, 2) ev_k(
    const unsigned short* __restrict__ concat, const unsigned short* __restrict__ WcT,
    float* __restrict__ partials)
{
  __shared__ __align__(16) unsigned char Abuf[128*128];   // bf16 [128 rows][64 k]
  __shared__ __align__(16) unsigned char Bbuf[256*128];   // bf16 [256 cols][64 k]
  const int tid = threadIdx.x, lane = tid & 63, w = tid >> 6;
  const int wm = w >> 2, wn = w & 3;
  const int yk = blockIdx.x & 7, xr = blockIdx.x >> 3;
  const int n0 = xr * 128;
  const int kbase = yk * 1792;

  f32x4 acc[4][4];
  #pragma unroll
  for (int mt = 0; mt < 4; ++mt)
    #pragma unroll
    for (int nt = 0; nt < 4; ++nt) acc[mt][nt] = (f32x4){0.f,0.f,0.f,0.f};

  const int aoff = tid * 32;
  const int arow = aoff >> 7;
  const unsigned char* asrc = (const unsigned char*)concat + (size_t)(n0 + arow)*28672 + (aoff & 127);
  const int bcol = tid >> 1, bhalf = (tid & 1) * 64;
  const unsigned char* bsrc = (const unsigned char*)WcT + (size_t)bcol*28672 + bhalf;

  // prologue: load chunk 0
  short8 ar0 = *(const short8*)(asrc + kbase*2);
  short8 ar1 = *(const short8*)(asrc + kbase*2 + 16);
  short8 br[4];
  #pragma unroll
  for (int kb = 0; kb < 4; ++kb) br[kb] = *(const short8*)(bsrc + kbase*2 + kb*16);

  #pragma unroll 1
  for (int ch = 0; ch < 28; ++ch){
    __syncthreads();
    *(short8*)(Abuf + aoff)      = ar0;
    *(short8*)(Abuf + aoff + 16) = ar1;
    #pragma unroll
    for (int kb = 0; kb < 4; ++kb) *(short8*)(Bbuf + bcol*128 + bhalf + kb*16) = br[kb];
    __syncthreads();
    if (ch < 27){  // issue next-chunk loads; latency hides under the MFMAs
      const int kk2 = (kbase + (ch + 1)*64) * 2;
      ar0 = *(const short8*)(asrc + kk2);
      ar1 = *(const short8*)(asrc + kk2 + 16);
      #pragma unroll
      for (int kb = 0; kb < 4; ++kb) br[kb] = *(const short8*)(bsrc + kk2 + kb*16);
    }
    #pragma unroll
    for (int kt = 0; kt < 2; ++kt){
      const int kby = kt*64 + (lane >> 4)*16;
      short8 afr[4], bfr[4];
      #pragma unroll
      for (int mt = 0; mt < 4; ++mt){
        int row = wm*64 + mt*16 + (lane & 15);
        afr[mt] = *(const short8*)(Abuf + ((row*128 + kby) ^ ((row & 7) << 4)));
      }
      #pragma unroll
      for (int nt = 0; nt < 4; ++nt){
        int col = wn*64 + nt*16 + (lane & 15);
        bfr[nt] = *(const short8*)(Bbuf + ((col*128 + kby) ^ ((col & 7) << 4)));
      }
      #pragma unroll
      for (int mt = 0; mt < 4; ++mt)
        #pragma unroll
        for (int nt = 0; nt < 4; ++nt)
          acc[mt][nt] = __builtin_amdgcn_mfma_f32_16x16x32_bf16(afr[mt], bfr[nt], acc[mt][nt], 0, 0, 0);
    }
  }
  float* dst = partials + (size_t)yk * (4096*256);
  #pragma unroll
  for (int mt = 0; mt < 4; ++mt){
    #pragma unroll
    for (int nt = 0; nt < 4; ++nt){
      #pragma unroll
      for (int i = 0; i < 4; ++i){
        int n = n0 + wm*64 + mt*16 + (lane >> 4)*4 + i;
        int col = wn*64 + nt*16 + (lane & 15);
        dst[(size_t)n*256 + col] = acc[mt][nt][i];
      }
    }
  }
}

// ---------------------------------------------------------------------------
// Reduce 8 partial slots, ev = tanh(.+bc), prob softmax + cost; also zeroes
// the out1/out2 row tails (replaces the host-side d_out memset — disjoint
// addresses from the computed slots, so no intra-block ordering needed).
// ---------------------------------------------------------------------------
__global__ void __launch_bounds__(256) heads_k(
    const float* __restrict__ partials, const float* __restrict__ bc,
    const float* __restrict__ Wprob, const float* __restrict__ bprob,
    const float* __restrict__ Wasso, const float* __restrict__ basso,
    float* __restrict__ out1, float* __restrict__ out2)
{
  __shared__ float evs[16][257];
  const int tid = threadIdx.x;
  const int nl = tid >> 4, part = tid & 15;
  const int n = blockIdx.x * 16 + nl;
  // zero tails first (overlaps with partials load latency)
  for (int idx = tid; idx < 1536; idx += 256){
    int s = idx / 96, j = idx - s*96;
    size_t r = (size_t)(blockIdx.x * 16 + s) * 96 + j;
    if (j >= 1) out1[r] = 0.f;
    if (j >= 2) out2[r] = 0.f;
  }
  #pragma unroll
  for (int q = 0; q < 4; ++q){
    const int c = part*16 + q*4;
    f32x4 s = {0.f,0.f,0.f,0.f};
    #pragma unroll
    for (int p = 0; p < 8; ++p){
      s += *(const f32x4*)(partials + (size_t)p*1048576 + (size_t)n*256 + c);
    }
    #pragma unroll
    for (int j = 0; j < 4; ++j) evs[nl][c + j] = tanhx_(s[j] + bc[c + j]);
  }
  __syncthreads();
  float s0 = 0.f, s1 = 0.f, s2 = 0.f;
  #pragma unroll
  for (int j = 0; j < 16; ++j){
    int c = part*16 + j;
    float e = evs[nl][c];
    s0 += e * Wprob[c*2];
    s1 += e * Wprob[c*2 + 1];
    s2 += e * Wasso[c];
  }
  s0 += __shfl_xor(s0, 1); s1 += __shfl_xor(s1, 1); s2 += __shfl_xor(s2, 1);
  s0 += __shfl_xor(s0, 2); s1 += __shfl_xor(s1, 2); s2 += __shfl_xor(s2, 2);
  s0 += __shfl_xor(s0, 4); s1 += __shfl_xor(s1, 4); s2 += __shfl_xor(s2, 4);
  s0 += __shfl_xor(s0, 8); s1 += __shfl_xor(s1, 8); s2 += __shfl_xor(s2, 8);
  if (part == 0){
    float a0 = s0 + bprob[0], a1 = s1 + bprob[1];
    float m = fmaxf(a0, a1);
    float e0 = ex2((a0 - m)*L2E), e1 = ex2((a1 - m)*L2E);
    float inv = __builtin_amdgcn_rcpf(e0 + e1);
    out2[(size_t)n*96 + 0] = e0 * inv;
    out2[(size_t)n*96 + 1] = e1 * inv;
    out1[(size_t)n*96 + 0] = s2 + basso[0];
  }
}

// ---------------------------------------------------------------------------
extern "C" void kernel_launch(void* const* d_in, const int* in_sizes, int n_in,
                              void* d_out, int out_size, void* d_ws, size_t ws_size,
                              hipStream_t stream)
{
  (void)in_sizes; (void)n_in; (void)ws_size; (void)out_size;
  const float* inputs = (const float*)d_in[0];
  const float* Wi     = (const float*)d_in[1];
  const float* Wh     = (const float*)d_in[2];
  const float* bl     = (const float*)d_in[3];
  const float* Wp     = (const float*)d_in[4];
  const float* bp     = (const float*)d_in[5];
  const float* W1     = (const float*)d_in[6];
  const float* b1     = (const float*)d_in[7];
  const float* W2     = (const float*)d_in[8];
  const float* b2     = (const float*)d_in[9];
  const float* Wc     = (const float*)d_in[10];
  const float* bc     = (const float*)d_in[11];
  const float* Wprob  = (const float*)d_in[12];
  const float* bprob  = (const float*)d_in[13];
  const float* Wasso  = (const float*)d_in[14];
  const float* basso  = (const float*)d_in[15];
  float* out = (float*)d_out;

  // workspace layout (r7-identical footprint: 158,597,120 B)
  char* ws = (char*)d_ws;
  unsigned short* concat = (unsigned short*)ws;                 // [4096][14336] bf16 swizzled
  unsigned short* WhT    = (unsigned short*)(ws + 117440512);   // [512][128] bf16 (gate-scaled)
  unsigned short* W2T    = (unsigned short*)(ws + 117571584);   // [256][256] bf16 raw
  unsigned short* WcT    = (unsigned short*)(ws + 117702656);   // [256][14336] bf16 swizzled
  float*          parts  = (float*)(ws + 125042688);            // [8][4096][256] f32

  dim3 blk(256);
  prep_k<<<4096, blk, 0, stream>>>(Wh, W2, Wc, inputs, WhT, W2T, WcT, out + 3*393216);
  lstm_k<<<256, dim3(512), 0, stream>>>(inputs, Wi, WhT, bl, Wp, bp, concat, out);
  t1t2_k<<<1536, blk, 0, stream>>>(out, W1, b1, W2T, b2, concat);
  ev_k<<<256, dim3(512), 0, stream>>>(concat, WcT, parts);
  heads_k<<<256, blk, 0, stream>>>(parts, bc, Wprob, bprob, Wasso, basso,
                                   out + 393216, out + 2*393216);
}